// Round 23
// baseline (261.699 us; speedup 1.0000x reference)
//
#include <hip/hip_runtime.h>

#define H 128
#define CAP 5120   // per-bucket edge capacity (mean 4096 -> 16 sigma)

typedef __attribute__((ext_vector_type(8))) short s16x8;
typedef __attribute__((ext_vector_type(2))) float f32x2;
typedef __attribute__((ext_vector_type(4))) float f32x4;

#define WAITBAR(N) asm volatile("s_waitcnt vmcnt(" #N ")\n\ts_barrier" ::: "memory")
#define BARO() asm volatile("s_barrier" ::: "memory")

__device__ __forceinline__ float bf2f(unsigned short u){
  unsigned x = ((unsigned)u) << 16;
  return __builtin_bit_cast(float, x);
}
__device__ __forceinline__ unsigned short f2bf(float f){
  unsigned u = __builtin_bit_cast(unsigned, f);
  u += 0x7fff + ((u >> 16) & 1);
  return (unsigned short)(u >> 16);
}

typedef __attribute__((address_space(1))) void gvoid;
typedef __attribute__((address_space(3))) void lvoid;
__device__ __forceinline__ void gload16(const void* g, void* l){
  __builtin_amdgcn_global_load_lds((gvoid*)(void*)g, (lvoid*)l, 16, 0, 0);
}

// ---- pass1 (edge bucketing) + convert + prep, 1-D grid ---- (unchanged from R22)
__global__ void pcfs_kernel(const float* x_, const float* h, const int* src, const int* dst,
                            const float* W_msg, const float* W_ih, const float* W_hh,
                            const float* b_ih, const float* b_hh,
                            unsigned short* xhs, unsigned char* xq,
                            unsigned* bucketArr, int* bucketCnt,
                            unsigned short* WmsgT, unsigned short* WbigT, float* biasb,
                            int NB, int YE, int nv, int E){
  int blk = blockIdx.x, tid = threadIdx.x;
  if(blk < YE){
    __shared__ int hcnt[256];
    __shared__ int hpos[256];
    hcnt[tid] = 0;
    __syncthreads();
    int base = blk*2048;
    unsigned pk[8]; int bk[8];
    #pragma unroll
    for(int it=0; it<8; ++it){
      int e = base + it*256 + tid;
      bk[it] = -1;
      if(e < E){
        int d = dst[e], s = src[e];
        pk[it] = ((unsigned)d << 16) | (unsigned)s;
        int b = d >> 8;
        bk[it] = b;
        atomicAdd(&hcnt[b], 1);
      }
    }
    __syncthreads();
    if(tid < NB){
      int c = hcnt[tid];
      hpos[tid] = (c > 0) ? atomicAdd(&bucketCnt[tid*32], c) : 0;
    }
    __syncthreads();
    #pragma unroll
    for(int it=0; it<8; ++it){
      if(bk[it] >= 0){
        int p = atomicAdd(&hpos[bk[it]], 1);
        if(p < CAP) bucketArr[(long)bk[it]*CAP + p] = pk[it];
      }
    }
    return;
  }
  long w0 = (long)(blk - YE)*2048 + tid;
  const int NW = 512*384;
  #pragma unroll 1
  for(int it=0; it<8; ++it){
    long w = w0 + (long)it*256;
    if(w < 2L*nv){
      const float* sp; long j; int add;
      if(w < nv){ sp = x_; j = w; add = 0; }
      else { sp = h; j = w - nv; add = 128; }
      float4 v = ((const float4*)sp)[j];
      ushort4 o; o.x=f2bf(v.x); o.y=f2bf(v.y); o.z=f2bf(v.z); o.w=f2bf(v.w);
      int node = (int)(j >> 5), col = add + ((int)j & 31)*4;
      int k = col >> 5, wc = col & 31;
      *(ushort4*)(xhs + (long)k*nv + node*32 + wc) = o;
      int r = __builtin_amdgcn_cvt_pk_fp8_f32(v.x, v.y, 0, false);
      r = __builtin_amdgcn_cvt_pk_fp8_f32(v.z, v.w, r, true);
      *(unsigned int*)(xq + (long)k*nv + node*32 + wc) = (unsigned)r;
      continue;
    }
    long i = w - 2L*nv;
    if(i < NW){
      int hf = (int)(i / 98304); int r1 = (int)(i % 98304);
      int kt = r1 / 16384; int r2 = r1 % 16384;
      int row = r2 / 64;   int r3 = r2 % 64;
      int cw = r3 >> 3;    int j = r3 & 7;
      int c = cw ^ (row & 7);
      int k = kt*64 + c*8 + j;
      int rp = hf*256 + row;
      int q = rp >> 2, g = rp & 3;
      float v;
      if(g < 3){
        int orow = g*128 + q;
        v = (k < 256) ? W_ih[orow*256 + k] : W_hh[orow*128 + (k-256)];
      } else {
        v = (k < 256) ? 0.f : W_hh[(256 + q)*128 + (k-256)];
      }
      WbigT[i] = f2bf(v);
    } else if(i < NW + 128*256){
      int j2 = (int)(i - NW);
      int kt = j2 / 8192; int r2 = j2 % 8192;
      int row = r2 / 64;  int r3 = r2 % 64;
      int cw = r3 >> 3;   int j = r3 & 7;
      int c = cw ^ (row & 7);
      int k = kt*64 + c*8 + j;
      WmsgT[j2] = f2bf(W_msg[row*256 + k]);
    } else if(i < NW + 128*256 + 512){
      int r = (int)(i - NW - 128*256);
      int q = r >> 2, g = r & 3;
      biasb[r] = (g < 3) ? (b_ih[g*128+q] + b_hh[g*128+q]) : b_hh[256+q];
    }
  }
}

// ---- pass2: per-bucket exclusive slot assignment ---- (unchanged)
__global__ void fill2_kernel(const unsigned* bucketArr, const int* bucketCnt,
                             int* rc, unsigned short* ss16, int N){
  __shared__ int lcnt[256];
  int b = blockIdx.x, tid = threadIdx.x;
  lcnt[tid] = 0;
  __syncthreads();
  int cnt = bucketCnt[b*32]; if(cnt > CAP) cnt = CAP;
  int nbase = b << 8;
  const unsigned* arr = bucketArr + (long)b*CAP;
  for(int i = tid; i < cnt; i += 256){
    unsigned e = arr[i];
    int d = e >> 16, s = e & 0xffff;
    int p = atomicAdd(&lcnt[d - nbase], 1);
    if(p < 128) ss16[((long)d << 7) + p] = (unsigned short)s;
  }
  __syncthreads();
  int node = nbase + tid;
  if(node < N) rc[node] = lcnt[tid];
}

// ---- XCD-sliced aggregation: fp8 table, 8-deep gather pipeline ---- (unchanged)
__global__ __launch_bounds__(256, 8) void agg_kernel(
    const unsigned char* xq, const int* rc, const unsigned short* ss16,
    unsigned short* Sb, int N){
  int tid = threadIdx.x;
  int group = tid >> 2, sub = tid & 3;
  int node = blockIdx.y*64 + group;
  if(node >= N) return;
  const unsigned char* base = xq + (long)blockIdx.x*(long)N*32;
  int cnt = rc[node];
  int use = (cnt < 128) ? cnt : 128;
  const long e0 = (long)node << 7;
  int co = sub*8;
  float a[8] = {0.f,0.f,0.f,0.f,0.f,0.f,0.f,0.f};
  #define ACC8(q) { \
    f32x2 l0 = __builtin_amdgcn_cvt_pk_f32_fp8((q).x, false); \
    f32x2 h0 = __builtin_amdgcn_cvt_pk_f32_fp8((q).x, true);  \
    f32x2 l1 = __builtin_amdgcn_cvt_pk_f32_fp8((q).y, false); \
    f32x2 h1 = __builtin_amdgcn_cvt_pk_f32_fp8((q).y, true);  \
    a[0]+=l0[0]; a[1]+=l0[1]; a[2]+=h0[0]; a[3]+=h0[1]; \
    a[4]+=l1[0]; a[5]+=l1[1]; a[6]+=h1[0]; a[7]+=h1[1]; }
  int i = 0;
  for(; i+7 < use; i += 8){
    ushort4 ia = *(const ushort4*)(ss16 + e0 + i);
    ushort4 ib = *(const ushort4*)(ss16 + e0 + i + 4);
    uint2 q0 = *(const uint2*)(base + (long)ia.x*32 + co);
    uint2 q1 = *(const uint2*)(base + (long)ia.y*32 + co);
    uint2 q2 = *(const uint2*)(base + (long)ia.z*32 + co);
    uint2 q3 = *(const uint2*)(base + (long)ia.w*32 + co);
    uint2 q4 = *(const uint2*)(base + (long)ib.x*32 + co);
    uint2 q5 = *(const uint2*)(base + (long)ib.y*32 + co);
    uint2 q6 = *(const uint2*)(base + (long)ib.z*32 + co);
    uint2 q7 = *(const uint2*)(base + (long)ib.w*32 + co);
    ACC8(q0); ACC8(q1); ACC8(q2); ACC8(q3);
    ACC8(q4); ACC8(q5); ACC8(q6); ACC8(q7);
  }
  for(; i+3 < use; i += 4){
    ushort4 ia = *(const ushort4*)(ss16 + e0 + i);
    uint2 q0 = *(const uint2*)(base + (long)ia.x*32 + co);
    uint2 q1 = *(const uint2*)(base + (long)ia.y*32 + co);
    uint2 q2 = *(const uint2*)(base + (long)ia.z*32 + co);
    uint2 q3 = *(const uint2*)(base + (long)ia.w*32 + co);
    ACC8(q0); ACC8(q1); ACC8(q2); ACC8(q3);
  }
  for(; i < use; ++i){
    int s0 = ss16[e0 + i];
    uint2 q0 = *(const uint2*)(base + (long)s0*32 + co);
    ACC8(q0);
  }
  #undef ACC8
  float inv = (cnt > 0) ? 1.0f/(float)cnt : 0.f;
  unsigned short o[8];
  #pragma unroll
  for(int j=0;j<8;++j) o[j] = f2bf(a[j]*inv);
  *(s16x8*)(Sb + (long)node*256 + blockIdx.x*32 + co) = *(const s16x8*)o;
}

// ---- fused v3: 512 thr (8 waves), 128 nodes/block, LDS 48KB -> 3 blocks/CU (one round).
// Drain-all schedule: stage -> vmcnt(0)+barrier -> compute -> barrier. Cross-block TLP
// hides latency. c via global cb; per-half K-order ends on own h-tile (resident for gates).
__global__ __launch_bounds__(512, 6) void fused_kernel(
    const unsigned short* xhs, const unsigned short* Sb, unsigned short* cb,
    const unsigned short* WmsgT, const unsigned short* WbigT,
    const float* b_msg, const float* biasb, const int* deg,
    float* outp, int NN){
  __shared__ __align__(16) char lds[49152];
  char* Wb = lds;            // 32KB W tile
  char* Nb = lds + 32768;    // 16KB node tile

  int tid = threadIdx.x;
  int lane = tid & 63, wv = tid >> 6;
  int l15 = lane & 15, l4 = lane >> 4;
  long nodebase = (long)blockIdx.x * 128;
  const long NV = (long)NN * 32;
  const f32x4 fz = {0.f,0.f,0.f,0.f};

  auto stageW1k = [&](int kt){   // phase1 W tile 16KB
    #pragma unroll
    for(int it=0; it<2; ++it){
      int slot = it*512 + tid;
      gload16(WmsgT + kt*8192 + slot*8, Wb + it*8192 + wv*1024);
    }
  };
  auto stageW3k = [&](int idx){  // phase3 W tile 32KB (idx = hf*6 + k-tile)
    #pragma unroll
    for(int it=0; it<4; ++it){
      int slot = it*512 + tid;
      gload16(WbigT + (long)idx*16384 + slot*8, Wb + it*8192 + wv*1024);
    }
  };
  auto stageS = [&](int koff){
    #pragma unroll
    for(int it=0; it<2; ++it){
      int slot = it*512 + tid;
      int row = slot >> 3, cw = slot & 7;
      int c = cw ^ (row & 7);
      long gr = nodebase + row; if(gr > NN-1) gr = NN-1;
      gload16(Sb + gr*256 + koff + c*8, Nb + it*8192 + wv*1024);
    }
  };
  auto stageX = [&](int koff){
    #pragma unroll
    for(int it=0; it<2; ++it){
      int slot = it*512 + tid;
      int row = slot >> 3, cw = slot & 7;
      int c = cw ^ (row & 7);
      int col = koff + c*8;
      int k = col >> 5, wc = col & 31;
      long gr = nodebase + row; if(gr > NN-1) gr = NN-1;
      gload16(xhs + (long)k*NV + gr*32 + wc, Nb + it*8192 + wv*1024);
    }
  };
  auto stageC = [&](int koff){
    #pragma unroll
    for(int it=0; it<2; ++it){
      int slot = it*512 + tid;
      int row = slot >> 3, cw = slot & 7;
      int c = cw ^ (row & 7);
      long gr = nodebase + row; if(gr > NN-1) gr = NN-1;
      gload16(cb + gr*128 + koff + c*8, Nb + it*8192 + wv*1024);
    }
  };
  auto stageK = [&](int kidx){   // kidx: 0=x0 1=x1 2=c0 3=c1 4=h0 5=h1
    if(kidx < 2) stageX(kidx*64);
    else if(kidx < 4) stageC((kidx-2)*64);
    else stageX(128 + (kidx-4)*64);
  };

  // ---------------- phase 1: c = Wmsg (128x256) @ Sb^T -> cb (global, bf16) ----------------
  int wm1 = wv >> 2, wn1 = wv & 3;   // 2x4: wave 64 feat x 32 nodes
  f32x4 acc1[4][2];
  #pragma unroll
  for(int m=0;m<4;++m){ acc1[m][0]=fz; acc1[m][1]=fz; }

  #pragma unroll
  for(int kt=0; kt<4; ++kt){
    stageW1k(kt); stageS(kt*64);
    WAITBAR(0);
    __builtin_amdgcn_s_setprio(1);
    #pragma unroll
    for(int kk=0; kk<2; ++kk){
      s16x8 af[4], bn[2];
      #pragma unroll
      for(int m=0;m<4;++m){
        int fr = wm1*64 + m*16 + l15;
        af[m] = *(const s16x8*)(Wb + fr*128 + (((kk*4+l4) ^ (fr&7))*16));
      }
      #pragma unroll
      for(int n=0;n<2;++n){
        int nr = wn1*32 + n*16 + l15;
        bn[n] = *(const s16x8*)(Nb + nr*128 + (((kk*4+l4) ^ (nr&7))*16));
      }
      #pragma unroll
      for(int m=0;m<4;++m)
        #pragma unroll
        for(int n=0;n<2;++n)
          acc1[m][n] = __builtin_amdgcn_mfma_f32_16x16x32_bf16(af[m], bn[n], acc1[m][n], 0, 0, 0);
    }
    __builtin_amdgcn_s_setprio(0);
    BARO();
  }
  // cb epilogue (deg-masked); stores drained by next WAITBAR(0)
  {
    float msk1[2];
    #pragma unroll
    for(int n=0;n<2;++n){
      long gn = nodebase + wn1*32 + n*16 + l15; if(gn > NN-1) gn = NN-1;
      msk1[n] = (deg[gn] > 0) ? 1.f : 0.f;
    }
    #pragma unroll
    for(int m=0;m<4;++m){
      int cc0 = wm1*64 + m*16 + l4*4;
      float4 bm = *(const float4*)(b_msg + cc0);
      #pragma unroll
      for(int n=0;n<2;++n){
        long gn = nodebase + wn1*32 + n*16 + l15;
        if(gn < NN){
          ushort4 o;
          o.x = f2bf((acc1[m][n][0] + bm.x)*msk1[n]);
          o.y = f2bf((acc1[m][n][1] + bm.y)*msk1[n]);
          o.z = f2bf((acc1[m][n][2] + bm.z)*msk1[n]);
          o.w = f2bf((acc1[m][n][3] + bm.w)*msk1[n]);
          *(ushort4*)(cb + gn*128 + cc0) = o;
        }
      }
    }
  }

  // ---------------- phase 3: 2 halves of P' = Wbig' @ [x|c|h]^T ----------------
  int wm = wv >> 1, wn = wv & 1;     // 4x2: wave 64 feat x 64 nodes
  #pragma unroll
  for(int hf=0; hf<2; ++hf){
    f32x4 acc3[4][4];
    #pragma unroll
    for(int m=0;m<4;++m)
      #pragma unroll
      for(int n=0;n<4;++n) acc3[m][n] = fz;

    #pragma unroll
    for(int kt=0; kt<6; ++kt){
      // K-order: last tile = this half's own h (resident for gates epilogue)
      int kk2 = (kt < 4) ? kt : ((kt == 4) ? (hf==0 ? 5 : 4) : (hf==0 ? 4 : 5));
      stageW3k(hf*6 + kk2); stageK(kk2);
      WAITBAR(0);
      __builtin_amdgcn_s_setprio(1);
      #pragma unroll
      for(int kk=0; kk<2; ++kk){
        s16x8 af[4], bn[4];
        #pragma unroll
        for(int m=0;m<4;++m){
          int fr = wm*64 + m*16 + l15;
          af[m] = *(const s16x8*)(Wb + fr*128 + (((kk*4+l4) ^ (fr&7))*16));
        }
        #pragma unroll
        for(int n=0;n<4;++n){
          int nr = wn*64 + n*16 + l15;
          bn[n] = *(const s16x8*)(Nb + nr*128 + (((kk*4+l4) ^ (nr&7))*16));
        }
        #pragma unroll
        for(int m=0;m<4;++m)
          #pragma unroll
          for(int n=0;n<4;++n)
            acc3[m][n] = __builtin_amdgcn_mfma_f32_16x16x32_bf16(af[m], bn[n], acc3[m][n], 0, 0, 0);
      }
      __builtin_amdgcn_s_setprio(0);
      BARO();
    }

    // gates epilogue: Nb holds h{hf} tile ([128 nodes][64 cols], swizzled)
    float hv[4][4];
    #pragma unroll
    for(int m=0;m<4;++m){
      int q = hf*64 + wm*16 + m*4 + l4;
      int hq = q & 63;
      #pragma unroll
      for(int n=0;n<4;++n){
        int node_l = wn*64 + n*16 + l15;
        unsigned short hu = *(const unsigned short*)(Nb + node_l*128 +
                              (((hq>>3) ^ (node_l&7))*16) + (hq&7)*2);
        hv[m][n] = bf2f(hu);
      }
    }
    __syncthreads();   // h reads complete before next half stages Nb

    #pragma unroll
    for(int m=0;m<4;++m){
      int q = hf*64 + wm*16 + m*4 + l4;
      float4 bb = *(const float4*)(biasb + q*4);
      #pragma unroll
      for(int n=0;n<4;++n){
        long gn = nodebase + wn*64 + n*16 + l15;
        float vr  = acc3[m][n][0] + bb.x;
        float vz  = acc3[m][n][1] + bb.y;
        float vsn = acc3[m][n][2] + bb.z;
        float vhn = acc3[m][n][3] + bb.w;
        float r = 1.f/(1.f + __expf(-vr));
        float z = 1.f/(1.f + __expf(-vz));
        float narg = vsn + (r - 1.f)*vhn;
        float nn2 = 2.f/(1.f + __expf(-2.f*narg)) - 1.f;
        if(gn < NN) outp[gn*128 + q] = (1.f - z)*nn2 + z*hv[m][n];
      }
    }
  }
}

extern "C" void kernel_launch(void* const* d_in, const int* in_sizes, int n_in,
                              void* d_out, int out_size, void* d_ws, size_t ws_size,
                              hipStream_t stream){
  const float* x     = (const float*)d_in[0];
  const float* h     = (const float*)d_in[1];
  const int*   src   = (const int*)d_in[2];
  const int*   dst   = (const int*)d_in[3];
  const float* W_msg = (const float*)d_in[4];
  const float* b_msg = (const float*)d_in[5];
  const float* W_ih  = (const float*)d_in[6];
  const float* W_hh  = (const float*)d_in[7];
  const float* b_ih  = (const float*)d_in[8];
  const float* b_hh  = (const float*)d_in[9];
  const int N = in_sizes[0] / H;
  const int E = in_sizes[2];
  float* out = (float*)d_out;

  char* p = (char*)d_ws;
  auto alloc = [&](size_t bytes)->char*{
    char* r = p; p += (bytes + 255) & ~(size_t)255; return r;
  };
  unsigned short* xhs   = (unsigned short*)alloc((size_t)N*256*2);
  unsigned short* Sb    = (unsigned short*)alloc((size_t)N*256*2);
  unsigned char*  xq    = (unsigned char*)alloc((size_t)N*256);
  unsigned short* cb    = (unsigned short*)alloc((size_t)N*128*2);
  unsigned short* WmsgT = (unsigned short*)alloc(128*256*2);
  unsigned short* WbigT = (unsigned short*)alloc(512*384*2);
  float*          biasb = (float*)alloc(512*4);
  int*            rc    = (int*)alloc((size_t)N*4);
  unsigned short* ss16  = (unsigned short*)alloc((size_t)N*128*2);
  int NB = (N + 255) >> 8;
  unsigned*       bktA  = (unsigned*)alloc((size_t)NB*CAP*4);
  int*            bktC  = (int*)alloc((size_t)NB*32*4);

  hipMemsetAsync(bktC, 0, (size_t)NB*32*4, stream);
  int nv = N*H/4;   // == N*32 == slice size (shorts for xhs, bytes for xq)
  const int NPREP = 512*384 + 128*256 + 512;
  int YE = (E + 2047)/2048;
  long convTotal = 2L*nv + NPREP;
  int YC = (int)((convTotal + 2047)/2048);
  pcfs_kernel<<<YE + YC, 256, 0, stream>>>(
      x, h, src, dst, W_msg, W_ih, W_hh, b_ih, b_hh,
      xhs, xq, bktA, bktC, WmsgT, WbigT, biasb, NB, YE, nv, E);

  fill2_kernel<<<NB, 256, 0, stream>>>(bktA, bktC, rc, ss16, N);

  dim3 gagg(8, (N + 63)/64);
  agg_kernel<<<gagg, 256, 0, stream>>>(xq, rc, ss16, Sb, N);

  int nblk = (N + 127)/128;
  fused_kernel<<<nblk, 512, 0, stream>>>(
      xhs, Sb, cb, WmsgT, WbigT, b_msg, biasb, rc, out, N);
}

// Round 24
// 128.589 us; speedup vs baseline: 2.0352x; 2.0352x over previous
//
#include <hip/hip_runtime.h>

#define H 128
#define CAP 5120   // per-bucket edge capacity (mean 4096 -> 16 sigma)

typedef __attribute__((ext_vector_type(8))) short s16x8;
typedef __attribute__((ext_vector_type(2))) float f32x2;
typedef __attribute__((ext_vector_type(4))) float f32x4;

#define WAITBAR(N) asm volatile("s_waitcnt vmcnt(" #N ")\n\ts_barrier" ::: "memory")
#define BARO() asm volatile("s_barrier" ::: "memory")

__device__ __forceinline__ float bf2f(unsigned short u){
  unsigned x = ((unsigned)u) << 16;
  return __builtin_bit_cast(float, x);
}
__device__ __forceinline__ unsigned short f2bf(float f){
  unsigned u = __builtin_bit_cast(unsigned, f);
  u += 0x7fff + ((u >> 16) & 1);
  return (unsigned short)(u >> 16);
}

typedef __attribute__((address_space(1))) void gvoid;
typedef __attribute__((address_space(3))) void lvoid;
__device__ __forceinline__ void gload16(const void* g, void* l){
  __builtin_amdgcn_global_load_lds((gvoid*)(void*)g, (lvoid*)l, 16, 0, 0);
}

// ---- pass1 (edge bucketing) + convert + prep, 1-D grid ----
__global__ void pcfs_kernel(const float* x_, const float* h, const int* src, const int* dst,
                            const float* W_msg, const float* W_ih, const float* W_hh,
                            const float* b_ih, const float* b_hh,
                            unsigned short* xhs, unsigned char* xq,
                            unsigned* bucketArr, int* bucketCnt,
                            unsigned short* WmsgT, unsigned short* WbigT, float* biasb,
                            int NB, int YE, int nv, int E){
  int blk = blockIdx.x, tid = threadIdx.x;
  if(blk < YE){
    __shared__ int hcnt[256];
    __shared__ int hpos[256];
    hcnt[tid] = 0;
    __syncthreads();
    int base = blk*2048;
    unsigned pk[8]; int bk[8];
    #pragma unroll
    for(int it=0; it<8; ++it){
      int e = base + it*256 + tid;
      bk[it] = -1;
      if(e < E){
        int d = dst[e], s = src[e];
        pk[it] = ((unsigned)d << 16) | (unsigned)s;
        int b = d >> 8;
        bk[it] = b;
        atomicAdd(&hcnt[b], 1);
      }
    }
    __syncthreads();
    if(tid < NB){
      int c = hcnt[tid];
      hpos[tid] = (c > 0) ? atomicAdd(&bucketCnt[tid*32], c) : 0;
    }
    __syncthreads();
    #pragma unroll
    for(int it=0; it<8; ++it){
      if(bk[it] >= 0){
        int p = atomicAdd(&hpos[bk[it]], 1);
        if(p < CAP) bucketArr[(long)bk[it]*CAP + p] = pk[it];
      }
    }
    return;
  }
  long w0 = (long)(blk - YE)*2048 + tid;
  const int NW = 512*384;
  #pragma unroll 1
  for(int it=0; it<8; ++it){
    long w = w0 + (long)it*256;
    if(w < 2L*nv){
      const float* sp; long j; int add;
      if(w < nv){ sp = x_; j = w; add = 0; }
      else { sp = h; j = w - nv; add = 128; }
      float4 v = ((const float4*)sp)[j];
      ushort4 o; o.x=f2bf(v.x); o.y=f2bf(v.y); o.z=f2bf(v.z); o.w=f2bf(v.w);
      int node = (int)(j >> 5), col = add + ((int)j & 31)*4;
      int k = col >> 5, wc = col & 31;
      *(ushort4*)(xhs + (long)k*nv + node*32 + wc) = o;
      int r = __builtin_amdgcn_cvt_pk_fp8_f32(v.x, v.y, 0, false);
      r = __builtin_amdgcn_cvt_pk_fp8_f32(v.z, v.w, r, true);
      *(unsigned int*)(xq + (long)k*nv + node*32 + wc) = (unsigned)r;
      continue;
    }
    long i = w - 2L*nv;
    if(i < NW){
      int hf = (int)(i / 98304); int r1 = (int)(i % 98304);
      int kt = r1 / 16384; int r2 = r1 % 16384;
      int row = r2 / 64;   int r3 = r2 % 64;
      int cw = r3 >> 3;    int j = r3 & 7;
      int c = cw ^ (row & 7);
      int k = kt*64 + c*8 + j;
      int rp = hf*256 + row;
      int q = rp >> 2, g = rp & 3;
      float v;
      if(g < 3){
        int orow = g*128 + q;
        v = (k < 256) ? W_ih[orow*256 + k] : W_hh[orow*128 + (k-256)];
      } else {
        v = (k < 256) ? 0.f : W_hh[(256 + q)*128 + (k-256)];
      }
      WbigT[i] = f2bf(v);
    } else if(i < NW + 128*256){
      int j2 = (int)(i - NW);
      int kt = j2 / 8192; int r2 = j2 % 8192;
      int row = r2 / 64;  int r3 = r2 % 64;
      int cw = r3 >> 3;   int j = r3 & 7;
      int c = cw ^ (row & 7);
      int k = kt*64 + c*8 + j;
      WmsgT[j2] = f2bf(W_msg[row*256 + k]);
    } else if(i < NW + 128*256 + 512){
      int r = (int)(i - NW - 128*256);
      int q = r >> 2, g = r & 3;
      biasb[r] = (g < 3) ? (b_ih[g*128+q] + b_hh[g*128+q]) : b_hh[256+q];
    }
  }
}

// ---- pass2: per-bucket exclusive slot assignment (LDS counters, NO global atomics) ----
__global__ void fill2_kernel(const unsigned* bucketArr, const int* bucketCnt,
                             int* rc, unsigned short* ss16, int N){
  __shared__ int lcnt[256];
  int b = blockIdx.x, tid = threadIdx.x;
  lcnt[tid] = 0;
  __syncthreads();
  int cnt = bucketCnt[b*32]; if(cnt > CAP) cnt = CAP;
  int nbase = b << 8;
  const unsigned* arr = bucketArr + (long)b*CAP;
  for(int i = tid; i < cnt; i += 256){
    unsigned e = arr[i];
    int d = e >> 16, s = e & 0xffff;
    int p = atomicAdd(&lcnt[d - nbase], 1);
    if(p < 128) ss16[((long)d << 7) + p] = (unsigned short)s;
  }
  __syncthreads();
  int node = nbase + tid;
  if(node < N) rc[node] = lcnt[tid];
}

// ---- XCD-sliced aggregation: fp8 table, 8-deep gather pipeline (plain loads) ----
__global__ __launch_bounds__(256, 8) void agg_kernel(
    const unsigned char* xq, const int* rc, const unsigned short* ss16,
    unsigned short* Sb, int N){
  int tid = threadIdx.x;
  int group = tid >> 2, sub = tid & 3;
  int node = blockIdx.y*64 + group;
  if(node >= N) return;
  const unsigned char* base = xq + (long)blockIdx.x*(long)N*32;
  int cnt = rc[node];
  int use = (cnt < 128) ? cnt : 128;
  const long e0 = (long)node << 7;
  int co = sub*8;
  float a[8] = {0.f,0.f,0.f,0.f,0.f,0.f,0.f,0.f};
  #define ACC8(q) { \
    f32x2 l0 = __builtin_amdgcn_cvt_pk_f32_fp8((q).x, false); \
    f32x2 h0 = __builtin_amdgcn_cvt_pk_f32_fp8((q).x, true);  \
    f32x2 l1 = __builtin_amdgcn_cvt_pk_f32_fp8((q).y, false); \
    f32x2 h1 = __builtin_amdgcn_cvt_pk_f32_fp8((q).y, true);  \
    a[0]+=l0[0]; a[1]+=l0[1]; a[2]+=h0[0]; a[3]+=h0[1]; \
    a[4]+=l1[0]; a[5]+=l1[1]; a[6]+=h1[0]; a[7]+=h1[1]; }
  int i = 0;
  for(; i+7 < use; i += 8){
    ushort4 ia = *(const ushort4*)(ss16 + e0 + i);
    ushort4 ib = *(const ushort4*)(ss16 + e0 + i + 4);
    uint2 q0 = *(const uint2*)(base + (long)ia.x*32 + co);
    uint2 q1 = *(const uint2*)(base + (long)ia.y*32 + co);
    uint2 q2 = *(const uint2*)(base + (long)ia.z*32 + co);
    uint2 q3 = *(const uint2*)(base + (long)ia.w*32 + co);
    uint2 q4 = *(const uint2*)(base + (long)ib.x*32 + co);
    uint2 q5 = *(const uint2*)(base + (long)ib.y*32 + co);
    uint2 q6 = *(const uint2*)(base + (long)ib.z*32 + co);
    uint2 q7 = *(const uint2*)(base + (long)ib.w*32 + co);
    ACC8(q0); ACC8(q1); ACC8(q2); ACC8(q3);
    ACC8(q4); ACC8(q5); ACC8(q6); ACC8(q7);
  }
  for(; i+3 < use; i += 4){
    ushort4 ia = *(const ushort4*)(ss16 + e0 + i);
    uint2 q0 = *(const uint2*)(base + (long)ia.x*32 + co);
    uint2 q1 = *(const uint2*)(base + (long)ia.y*32 + co);
    uint2 q2 = *(const uint2*)(base + (long)ia.z*32 + co);
    uint2 q3 = *(const uint2*)(base + (long)ia.w*32 + co);
    ACC8(q0); ACC8(q1); ACC8(q2); ACC8(q3);
  }
  for(; i < use; ++i){
    int s0 = ss16[e0 + i];
    uint2 q0 = *(const uint2*)(base + (long)s0*32 + co);
    ACC8(q0);
  }
  #undef ACC8
  float inv = (cnt > 0) ? 1.0f/(float)cnt : 0.f;
  unsigned short o[8];
  #pragma unroll
  for(int j=0;j<8;++j) o[j] = f2bf(a[j]*inv);
  *(s16x8*)(Sb + (long)node*256 + blockIdx.x*32 + co) = *(const s16x8*)o;
}

// ---- fused: msg-GEMM -> c(LDS) -> GRU-GEMM (2 output halves) -> gates -> out ----
// R22 version (best measured). 512 threads (8 waves), 128 nodes/block, LDS 128KB,
// counted-vmcnt pipeline, XOR-swizzled ldsO.
__global__ __launch_bounds__(512, 2) void fused_kernel(
    const unsigned short* xhs, const unsigned short* Sb,
    const unsigned short* WmsgT, const unsigned short* WbigT,
    const float* b_msg, const float* biasb, const int* deg,
    float* outp, int NN){
  __shared__ __align__(16) char lds[131072];
  char* W0 = lds;
  char* W1 = lds + 32768;
  char* N0 = lds + 65536;
  char* N1 = lds + 81920;
  char* ldsC = lds + 98304;
  float* ldsO = (float*)(lds + 32768);

  int tid = threadIdx.x;
  int lane = tid & 63, wv = tid >> 6;
  int l15 = lane & 15, l4 = lane >> 4;
  long nodebase = (long)blockIdx.x * 128;
  const long NV = (long)NN * 32;   // slice size in shorts
  const f32x4 fz = {0.f,0.f,0.f,0.f};

  auto stageS = [&](int koff, char* dst){
    #pragma unroll
    for(int it=0; it<2; ++it){
      int slot = it*512 + tid;
      int row = slot >> 3, cw = slot & 7;
      int c = cw ^ (row & 7);
      long gr = nodebase + row; if(gr > NN-1) gr = NN-1;
      gload16(Sb + gr*256 + koff + c*8, dst + it*8192 + wv*1024);
    }
  };
  auto stageX = [&](int koff, char* dst){
    #pragma unroll
    for(int it=0; it<2; ++it){
      int slot = it*512 + tid;
      int row = slot >> 3, cw = slot & 7;
      int c = cw ^ (row & 7);
      int col = koff + c*8;
      int k = col >> 5, wc = col & 31;
      long gr = nodebase + row; if(gr > NN-1) gr = NN-1;
      gload16(xhs + (long)k*NV + gr*32 + wc, dst + it*8192 + wv*1024);
    }
  };
  auto stageW1k = [&](int kt, char* dst){
    #pragma unroll
    for(int it=0; it<2; ++it){
      int slot = it*512 + tid;
      gload16(WmsgT + kt*8192 + slot*8, dst + it*8192 + wv*1024);
    }
  };
  auto stageW3k = [&](int idx, char* dst){
    #pragma unroll
    for(int it=0; it<4; ++it){
      int slot = it*512 + tid;
      gload16(WbigT + (long)idx*16384 + slot*8, dst + it*8192 + wv*1024);
    }
  };

  // ---------------- phase 1: c = Wmsg (128x256) @ Sb^T ----------------
  int wm1 = wv >> 2, wn1 = wv & 3;
  f32x4 acc1[4][2];
  #pragma unroll
  for(int m=0;m<4;++m){ acc1[m][0]=fz; acc1[m][1]=fz; }

  auto compute1 = [&](const char* Wb, const char* Nb){
    __builtin_amdgcn_s_setprio(1);
    #pragma unroll
    for(int kk=0; kk<2; ++kk){
      s16x8 af[4], bn[2];
      #pragma unroll
      for(int m=0;m<4;++m){
        int fr = wm1*64 + m*16 + l15;
        af[m] = *(const s16x8*)(Wb + fr*128 + (((kk*4+l4) ^ (fr&7))*16));
      }
      #pragma unroll
      for(int n=0;n<2;++n){
        int nr = wn1*32 + n*16 + l15;
        bn[n] = *(const s16x8*)(Nb + nr*128 + (((kk*4+l4) ^ (nr&7))*16));
      }
      #pragma unroll
      for(int m=0;m<4;++m)
        #pragma unroll
        for(int n=0;n<2;++n)
          acc1[m][n] = __builtin_amdgcn_mfma_f32_16x16x32_bf16(af[m], bn[n], acc1[m][n], 0, 0, 0);
    }
    __builtin_amdgcn_s_setprio(0);
  };

  stageW1k(0, W0); stageS(0, N0);
  stageW1k(1, W1); stageS(64, N1);
  WAITBAR(4); compute1(W0, N0); BARO();
  stageW1k(2, W0); stageS(128, N0);
  WAITBAR(4); compute1(W1, N1); BARO();
  stageW1k(3, W1); stageS(192, N1);
  WAITBAR(4); compute1(W0, N0); BARO();
  stageW3k(0, W0); stageX(0, N0);
  WAITBAR(6); compute1(W1, N1); BARO();

  // phase 2: bias + deg-mask, bf16, write c-tile to LDS (swizzled)
  #pragma unroll
  for(int n=0;n<2;++n){
    int node_l = wn1*32 + n*16 + l15;
    long gn = nodebase + node_l; if(gn > NN-1) gn = NN-1;
    int dg = deg[gn];
    float msk = (dg > 0) ? 1.f : 0.f;
    #pragma unroll
    for(int m=0;m<4;++m){
      int ccb = wm1*64 + m*16 + l4*4;
      float4 bm = *(const float4*)(b_msg + ccb);
      ushort4 o;
      o.x = f2bf((acc1[m][n][0] + bm.x)*msk);
      o.y = f2bf((acc1[m][n][1] + bm.y)*msk);
      o.z = f2bf((acc1[m][n][2] + bm.z)*msk);
      o.w = f2bf((acc1[m][n][3] + bm.w)*msk);
      *(ushort4*)(ldsC + node_l*256 + (((ccb>>3) ^ (node_l&7))*16) + (ccb&4)*2) = o;
    }
  }
  __syncthreads();

  // ---------------- phase 3: two output halves of P' = Wbig' @ [x|c|h]^T ----------------
  int wm = wv >> 1, wn = wv & 1;

  auto runHalf = [&](int hf){
    f32x4 acc3[4][4];
    #pragma unroll
    for(int m=0;m<4;++m)
      #pragma unroll
      for(int n=0;n<4;++n) acc3[m][n] = fz;

    auto computeN = [&](const char* Wb, const char* Nb){
      __builtin_amdgcn_s_setprio(1);
      #pragma unroll
      for(int kk=0; kk<2; ++kk){
        s16x8 af[4], bn[4];
        #pragma unroll
        for(int m=0;m<4;++m){
          int fr = wm*64 + m*16 + l15;
          af[m] = *(const s16x8*)(Wb + fr*128 + (((kk*4+l4) ^ (fr&7))*16));
        }
        #pragma unroll
        for(int n=0;n<4;++n){
          int nr = wn*64 + n*16 + l15;
          bn[n] = *(const s16x8*)(Nb + nr*128 + (((kk*4+l4) ^ (nr&7))*16));
        }
        #pragma unroll
        for(int m=0;m<4;++m)
          #pragma unroll
          for(int n=0;n<4;++n)
            acc3[m][n] = __builtin_amdgcn_mfma_f32_16x16x32_bf16(af[m], bn[n], acc3[m][n], 0, 0, 0);
      }
      __builtin_amdgcn_s_setprio(0);
    };
    auto computeC = [&](const char* Wb, int ktc){
      __builtin_amdgcn_s_setprio(1);
      #pragma unroll
      for(int kk=0; kk<2; ++kk){
        s16x8 af[4], bn[4];
        #pragma unroll
        for(int m=0;m<4;++m){
          int fr = wm*64 + m*16 + l15;
          af[m] = *(const s16x8*)(Wb + fr*128 + (((kk*4+l4) ^ (fr&7))*16));
        }
        #pragma unroll
        for(int n=0;n<4;++n){
          int nr = wn*64 + n*16 + l15;
          bn[n] = *(const s16x8*)(ldsC + nr*256 + (((ktc*8 + kk*4 + l4) ^ (nr&7))*16));
        }
        #pragma unroll
        for(int m=0;m<4;++m)
          #pragma unroll
          for(int n=0;n<4;++n)
            acc3[m][n] = __builtin_amdgcn_mfma_f32_16x16x32_bf16(af[m], bn[n], acc3[m][n], 0, 0, 0);
      }
      __builtin_amdgcn_s_setprio(0);
    };

    if(hf == 1) stageX(0, N0);
    stageW3k(hf*6+1, W1); stageX(64, N1);
    WAITBAR(6); computeN(W0, N0); BARO();
    stageW3k(hf*6+2, W0);
    WAITBAR(4); computeN(W1, N1); BARO();
    stageW3k(hf*6+3, W1);
    WAITBAR(4); computeC(W0, 0); BARO();
    stageW3k(hf*6+4, W0); stageX(128, N0);
    WAITBAR(6); computeC(W1, 1); BARO();
    stageW3k(hf*6+5, W1); stageX(192, N1);
    WAITBAR(6); computeN(W0, N0); BARO();
    if(hf == 0){
      stageW3k(6, W0);
      WAITBAR(4); computeN(W1, N1); BARO();
    } else {
      WAITBAR(0); computeN(W1, N1); BARO();
    }

    const char* hbuf = (hf == 0) ? N0 : N1;
    #pragma unroll
    for(int m=0;m<4;++m){
      int q = hf*64 + wm*16 + m*4 + l4;
      int ql = q & 63;
      float4 bb = *(const float4*)(biasb + q*4);
      #pragma unroll
      for(int n=0;n<4;++n){
        int node_l = wn*64 + n*16 + l15;
        unsigned short hu = *(const unsigned short*)(hbuf + node_l*128 +
                              (((ql>>3) ^ (node_l&7))*16) + (ql&7)*2);
        float hv = bf2f(hu);
        float vr  = acc3[m][n][0] + bb.x;
        float vz  = acc3[m][n][1] + bb.y;
        float vsn = acc3[m][n][2] + bb.z;
        float vhn = acc3[m][n][3] + bb.w;
        float r = 1.f/(1.f + __expf(-vr));
        float z = 1.f/(1.f + __expf(-vz));
        float narg = vsn + (r - 1.f)*vhn;
        float nn2 = 2.f/(1.f + __expf(-2.f*narg)) - 1.f;
        ldsO[node_l*64 + (ql ^ ((node_l & 15) << 2))] = (1.f - z)*nn2 + z*hv;
      }
    }
    __syncthreads();

    #pragma unroll
    for(int it=0; it<4; ++it){
      int slot = it*512 + tid;
      int node_l = slot >> 4, f4 = slot & 15;
      long gn = nodebase + node_l;
      if(gn < NN){
        float4 v = *(const float4*)(ldsO + node_l*64 + (((f4*4) ^ ((node_l & 15) << 2))));
        *(float4*)(outp + gn*128 + hf*64 + f4*4) = v;
      }
    }
    __syncthreads();
  };

  runHalf(0);
  runHalf(1);
}

extern "C" void kernel_launch(void* const* d_in, const int* in_sizes, int n_in,
                              void* d_out, int out_size, void* d_ws, size_t ws_size,
                              hipStream_t stream){
  const float* x     = (const float*)d_in[0];
  const float* h     = (const float*)d_in[1];
  const int*   src   = (const int*)d_in[2];
  const int*   dst   = (const int*)d_in[3];
  const float* W_msg = (const float*)d_in[4];
  const float* b_msg = (const float*)d_in[5];
  const float* W_ih  = (const float*)d_in[6];
  const float* W_hh  = (const float*)d_in[7];
  const float* b_ih  = (const float*)d_in[8];
  const float* b_hh  = (const float*)d_in[9];
  const int N = in_sizes[0] / H;
  const int E = in_sizes[2];
  float* out = (float*)d_out;

  char* p = (char*)d_ws;
  auto alloc = [&](size_t bytes)->char*{
    char* r = p; p += (bytes + 255) & ~(size_t)255; return r;
  };
  unsigned short* xhs   = (unsigned short*)alloc((size_t)N*256*2);
  unsigned short* Sb    = (unsigned short*)alloc((size_t)N*256*2);
  unsigned char*  xq    = (unsigned char*)alloc((size_t)N*256);
  unsigned short* WmsgT = (unsigned short*)alloc(128*256*2);
  unsigned short* WbigT = (unsigned short*)alloc(512*384*2);
  float*          biasb = (float*)alloc(512*4);
  int*            rc    = (int*)alloc((size_t)N*4);
  unsigned short* ss16  = (unsigned short*)alloc((size_t)N*128*2);
  int NB = (N + 255) >> 8;
  unsigned*       bktA  = (unsigned*)alloc((size_t)NB*CAP*4);
  int*            bktC  = (int*)alloc((size_t)NB*32*4);

  hipMemsetAsync(bktC, 0, (size_t)NB*32*4, stream);
  int nv = N*H/4;   // == N*32 == slice size (shorts for xhs, bytes for xq)
  const int NPREP = 512*384 + 128*256 + 512;
  int YE = (E + 2047)/2048;
  long convTotal = 2L*nv + NPREP;
  int YC = (int)((convTotal + 2047)/2048);
  pcfs_kernel<<<YE + YC, 256, 0, stream>>>(
      x, h, src, dst, W_msg, W_ih, W_hh, b_ih, b_hh,
      xhs, xq, bktA, bktC, WmsgT, WbigT, biasb, NB, YE, nv, E);

  fill2_kernel<<<NB, 256, 0, stream>>>(bktA, bktC, rc, ss16, N);

  dim3 gagg(8, (N + 63)/64);
  agg_kernel<<<gagg, 256, 0, stream>>>(xq, rc, ss16, Sb, N);

  int nblk = (N + 127)/128;
  fused_kernel<<<nblk, 512, 0, stream>>>(
      xhs, Sb, WmsgT, WbigT, b_msg, biasb, rc, out, N);
}